// Round 11
// baseline (710.566 us; speedup 1.0000x reference)
//
#include <hip/hip_runtime.h>
#include <hip/hip_bf16.h>

// ---------------------------------------------------------------------------
// StreamingQwenMoE round 11: OCCUPANCY. r7 serial structure + loop verbatim,
// but 512-thread blocks (8 waves, 4x2) at the SAME 81920-byte LDS:
//   2 blocks/CU x 8 waves = 16 waves/CU (4/SIMD) -- 2x round-7's residency.
//   Per-wave tile 32 rows (m=0..1), per-thread staging halved (A 2 DMA,
//   B BCH=2 dual / 4 single), uniform counted vmcnt(6).
//   __launch_bounds__(512,4) pins VGPR <= 128 (required for 16 waves/CU).
// Rationale: every GEMM since r2 pins at MfmaUtil 15-21 / VALU <=21 /
// HBM <=17 / Occ 16-18 -- all-low = latency-bound; occupancy is the one
// untested knob. r10 co-scheduling was null (reverted); r9 overlap regressed
// (reverted); LDS must stay <= 81920 (r4/r5, measured twice).
// Verified carried: router/top8/dispatch, SwiGLU, C/D layout, XOR swizzle,
// bijective XCD swizzle, atomic-free pair-buffer combine.
// ---------------------------------------------------------------------------

#define TT   2048
#define DD   2048
#define DFF  768
#define DSH  2048
#define EE   32
#define KTOP 8
#define CAP  1024

typedef _Float16 half8  __attribute__((ext_vector_type(8)));
typedef _Float16 half4v __attribute__((ext_vector_type(4)));
typedef float    f32x4  __attribute__((ext_vector_type(4)));

// ---------------- init ------------------------------------------------------
__global__ __launch_bounds__(256) void k_init(int* __restrict__ cnt,
                                              int* __restrict__ slot_tok) {
  int i = blockIdx.x * 256 + threadIdx.x;
  if (i < EE * CAP) slot_tok[i] = 0;
  if (i < EE) cnt[i] = 0;
}

// ---------------- f32 -> f16 cast -------------------------------------------
__global__ __launch_bounds__(256) void k_cast(const float* __restrict__ in,
                                              _Float16* __restrict__ out) {
  int i = blockIdx.x * 256 + threadIdx.x;
  float4 v = ((const float4*)in)[i];
  half4v h = { (_Float16)v.x, (_Float16)v.y, (_Float16)v.z, (_Float16)v.w };
  ((half4v*)out)[i] = h;
}

// ---------------- router: logits, top8, renorm, dispatch --------------------
__global__ __launch_bounds__(64) void k_router(
    const float* __restrict__ x, const float* __restrict__ rw,
    const float* __restrict__ wshg,
    float* __restrict__ shg, int* __restrict__ cnt,
    int* __restrict__ slot_tok, float* __restrict__ slot_w,
    int* __restrict__ slot_pair, int* __restrict__ pair_pos) {
  int t = blockIdx.x;
  int lane = threadIdx.x;
  const float* xr = x + (size_t)t * DD;
  float xv[32];
#pragma unroll
  for (int j = 0; j < 32; ++j) xv[j] = xr[lane + j * 64];

  __shared__ float lg[EE];
  for (int e = 0; e < EE; ++e) {
    const float* we = rw + (size_t)e * DD;
    float s = 0.f;
#pragma unroll
    for (int j = 0; j < 32; ++j) s += xv[j] * we[lane + j * 64];
#pragma unroll
    for (int off = 32; off > 0; off >>= 1) s += __shfl_down(s, off);
    if (lane == 0) lg[e] = s;
  }
  {
    float s = 0.f;
#pragma unroll
    for (int j = 0; j < 32; ++j) s += xv[j] * wshg[lane + j * 64];
#pragma unroll
    for (int off = 32; off > 0; off >>= 1) s += __shfl_down(s, off);
    if (lane == 0) shg[t] = 1.f / (1.f + expf(-s));
  }
  if (lane == 0) {
    unsigned used = 0;
    int sel[KTOP];
    float val[KTOP];
    for (int k = 0; k < KTOP; ++k) {
      float bv = -1e30f; int bi = 0;
      for (int e = 0; e < EE; ++e)
        if (!((used >> e) & 1) && lg[e] > bv) { bv = lg[e]; bi = e; }
      used |= (1u << bi);
      sel[k] = bi; val[k] = bv;
    }
    float mx = val[0], sum = 0.f;
    for (int k = 0; k < KTOP; ++k) { val[k] = expf(val[k] - mx); sum += val[k]; }
    float inv = 1.f / sum;
    for (int k = 0; k < KTOP; ++k) {
      int e = sel[k];
      int pos = atomicAdd(&cnt[e], 1);
      pair_pos[t * KTOP + k] = pos;
      if (pos < CAP) {
        slot_tok[e * CAP + pos] = t;
        slot_w[e * CAP + pos] = val[k] * inv;
        slot_pair[e * CAP + pos] = t * KTOP + k;
      }
    }
  }
}

// ---------------- grouped GEMM: C = A (rows x K, f16) * B (N x K, f32)^T ----
// r7 loop structure, 512-thread / 8-wave (4x2) geometry.
// sA[3] via global_load_lds (pre-swizzled source), sB[2] reg-staged with
// fused dequant; 1 s_barrier per K-tile; uniform counted vmcnt(6).
// EPI: 0 = f16 OutH (SwiGLU if DUAL); 1 = f16 scatter w*val -> OutH[pair*DD];
//      2 = OutF[row] += shg[row]*val.
template<bool DUAL, bool GATHER, bool DEQ, int EPI, int NPB, int MBB, int KDIM>
__global__ __launch_bounds__(512, 4) void k_gemm(
    const _Float16* __restrict__ A,
    const float* __restrict__ B0f, const float* __restrict__ B1f,
    const float* __restrict__ S0, const float* __restrict__ S1,
    int sCols, int sStrideE,
    _Float16* __restrict__ OutH, float* __restrict__ OutF,
    const float* __restrict__ shg,
    int ldA, int ldOut,
    long long strideAE, long long strideBE, long long strideOE,
    const int* __restrict__ cnt, int rowsConst,
    const int* __restrict__ slot_tok, const float* __restrict__ slot_w) {
  constexpr int BK = 64;
  constexpr int KT = KDIM / BK;              // 32 / 12 (even)
  constexpr int NF = DUAL ? 2 : 4;
  constexpr int BN = DUAL ? 64 : 128;
  constexpr int BCH = DUAL ? 2 : 4;          // float4 staging chunks / thread / op

  // bijective XCD swizzle: all m-blocks of pair (n,e) adjacent on one XCD
  const int f = blockIdx.x;
  const int xcd = f & 7;
  const int t0 = f >> 3;
  const int mb = t0 % MBB;
  const int pp = t0 / MBB;
  const int p  = pp * 8 + xcd;               // (NPB*E) % 8 == 0 for all uses
  const int nb = p % NPB;
  const int e  = p / NPB;

  int rows = cnt ? (cnt[e] > CAP ? CAP : cnt[e]) : rowsConst;
  const int rowBase = mb * 128;
  if (rowBase >= rows) return;
  const int nBase = nb * BN;

  const int tid = threadIdx.x;
  const int lane = tid & 63;
  const int wave = tid >> 6;                 // 0..7
  const int wr = wave >> 1;                  // 0..3 : 32 rows each
  const int wc = wave & 1;                   // 0..1

  __shared__ __align__(16) _Float16 sA[3][8192];   // 48 KB
  __shared__ __align__(16) _Float16 sB[2][8192];   // 32 KB (total 81920 B)

  const _Float16* Ae = A + (GATHER ? 0 : (long long)e * strideAE);
  const float* B0e = B0f + (long long)e * strideBE;
  const float* B1e = DUAL ? (B1f + (long long)e * strideBE) : nullptr;
  const float* S0e = DEQ ? (S0 + (long long)e * sStrideE) : nullptr;
  const float* S1e = (DEQ && DUAL) ? (S1 + (long long)e * sStrideE) : nullptr;
  const int sRow = DEQ ? (nBase >> 7) * sCols : 0;

  // A staging (global_load_lds): LDS dest linear, source col pre-swizzled
  int aByte[2];
#pragma unroll
  for (int i = 0; i < 2; ++i) {
    int c = tid + i * 512;                   // 16B chunk id [0,1024)
    int row = c >> 3;                        // tile row 0..127
    int colB = ((c & 7) << 4) ^ ((row & 7) << 4);
    int src = GATHER ? slot_tok[e * CAP + rowBase + row] : (rowBase + row);
    aByte[i] = src * (2 * ldA) + colB;
  }
  // B staging: reg->cvt->swizzled LDS write
  int bOff[BCH], wByte[BCH];
#pragma unroll
  for (int i = 0; i < BCH; ++i) {
    int c = tid + i * 512;
    int rn = c >> 4;                         // [0, BN)
    int c4 = (c & 15) << 2;                  // f32 col 0..60 step 4
    bOff[i] = (nBase + rn) * KDIM + c4;
    wByte[i] = ((rn << 7) + (c4 << 1)) ^ ((rn & 7) << 4);
  }

  f32x4 accG[2][NF];
  f32x4 accU[DUAL ? 2 : 1][NF];
#pragma unroll
  for (int m = 0; m < 2; ++m)
#pragma unroll
    for (int n = 0; n < NF; ++n) {
      accG[m][n] = (f32x4){0.f, 0.f, 0.f, 0.f};
      if constexpr (DUAL) accU[m][n] = (f32x4){0.f, 0.f, 0.f, 0.f};
    }

  auto stageA = [&](int kt, int buf) {       // 2 DMA ops
#pragma unroll
    for (int i = 0; i < 2; ++i) {
      __builtin_amdgcn_global_load_lds(
          (const __attribute__((address_space(1))) void*)
              ((const char*)Ae + aByte[i] + kt * (BK * 2)),
          (__attribute__((address_space(3))) void*)&sA[buf][(tid + i * 512) * 8],
          16, 0, 0);
    }
  };
  auto loadB = [&](int kt, float4 (&r0)[BCH], float4 (&r1)[BCH]) {  // 4 loads
    const int ko = kt * BK;
#pragma unroll
    for (int i = 0; i < BCH; ++i) r0[i] = *(const float4*)(B0e + bOff[i] + ko);
    if constexpr (DUAL) {
#pragma unroll
      for (int i = 0; i < BCH; ++i) r1[i] = *(const float4*)(B1e + bOff[i] + ko);
    }
  };
  auto storeB = [&](int kt, float4 (&r0)[BCH], float4 (&r1)[BCH]) {
    float s0 = 1.f, s1 = 1.f;
    if constexpr (DEQ) {
      s0 = S0e[sRow + (kt >> 1)];
      if constexpr (DUAL) s1 = S1e[sRow + (kt >> 1)];
    }
    char* base = (char*)&sB[kt & 1][0];
#pragma unroll
    for (int i = 0; i < BCH; ++i) {
      half4v h = { (_Float16)(r0[i].x * s0), (_Float16)(r0[i].y * s0),
                   (_Float16)(r0[i].z * s0), (_Float16)(r0[i].w * s0) };
      *(half4v*)(base + wByte[i]) = h;
      if constexpr (DUAL) {
        half4v h1 = { (_Float16)(r1[i].x * s1), (_Float16)(r1[i].y * s1),
                      (_Float16)(r1[i].z * s1), (_Float16)(r1[i].w * s1) };
        *(half4v*)(base + 8192 + wByte[i]) = h1;
      }
    }
  };
  auto computeTile = [&](int ia, int ib) {
    const char* pA = (const char*)&sA[ia][0];
    const char* pB = (const char*)&sB[ib][0];
#pragma unroll
    for (int kk = 0; kk < 2; ++kk) {
      const int koff = kk * 32 + (lane >> 4) * 8;    // f16 elems
      half8 a[2];
#pragma unroll
      for (int m = 0; m < 2; ++m) {
        int r = wr * 32 + m * 16 + (lane & 15);
        int byt = ((r << 7) + (koff << 1)) ^ ((r & 7) << 4);
        a[m] = *(const half8*)(pA + byt);
      }
      if constexpr (DUAL) {
        half8 bg[2], bu[2];
#pragma unroll
        for (int n = 0; n < 2; ++n) {
          int rn = wc * 32 + n * 16 + (lane & 15);
          int byt = ((rn << 7) + (koff << 1)) ^ ((rn & 7) << 4);
          bg[n] = *(const half8*)(pB + byt);
          bu[n] = *(const half8*)(pB + 8192 + byt);
        }
#pragma unroll
        for (int m = 0; m < 2; ++m)
#pragma unroll
          for (int n = 0; n < 2; ++n) {
            accG[m][n] = __builtin_amdgcn_mfma_f32_16x16x32_f16(a[m], bg[n], accG[m][n], 0, 0, 0);
            accU[m][n] = __builtin_amdgcn_mfma_f32_16x16x32_f16(a[m], bu[n], accU[m][n], 0, 0, 0);
          }
      } else {
        half8 b[4];
#pragma unroll
        for (int n = 0; n < 4; ++n) {
          int rn = wc * 64 + n * 16 + (lane & 15);
          int byt = ((rn << 7) + (koff << 1)) ^ ((rn & 7) << 4);
          b[n] = *(const half8*)(pB + byt);
        }
#pragma unroll
        for (int m = 0; m < 2; ++m)
#pragma unroll
          for (int n = 0; n < 4; ++n)
            accG[m][n] = __builtin_amdgcn_mfma_f32_16x16x32_f16(a[m], b[n], accG[m][n], 0, 0, 0);
      }
    }
  };

  // even/odd named register sets (rule #20)
  float4 rbE0[BCH], rbE1[BCH], rbO0[BCH], rbO1[BCH];

  // prologue: tiles 0 and 1 in flight (6 ops each; pinned issue groups)
  stageA(0, 0); loadB(0, rbE0, rbE1);
  __builtin_amdgcn_sched_barrier(0);
  stageA(1, 1); loadB(1, rbO0, rbO1);
  __builtin_amdgcn_sched_barrier(0);

  int bufC = 0;   // sA buffer of current tile
  int bufW = 2;   // sA buffer for next issued tile

  for (int kt = 0; kt < KT; kt += 2) {
    // ---------- even tile kt ----------
    if (kt + 1 < KT) { asm volatile("s_waitcnt vmcnt(6)" ::: "memory"); }
    else             { asm volatile("s_waitcnt vmcnt(0)" ::: "memory"); }
    __builtin_amdgcn_sched_barrier(0);
    storeB(kt, rbE0, rbE1);
    asm volatile("s_waitcnt lgkmcnt(0)" ::: "memory");
    __builtin_amdgcn_sched_barrier(0);
    __builtin_amdgcn_s_barrier();
    __builtin_amdgcn_sched_barrier(0);
    if (kt + 2 < KT) { stageA(kt + 2, bufW); loadB(kt + 2, rbE0, rbE1); }
    __builtin_amdgcn_sched_barrier(0);
    computeTile(bufC, 0);
    bufC = (bufC == 2) ? 0 : bufC + 1;
    bufW = (bufW == 2) ? 0 : bufW + 1;

    // ---------- odd tile kt+1 ----------
    if (kt + 2 < KT) { asm volatile("s_waitcnt vmcnt(6)" ::: "memory"); }
    else             { asm volatile("s_waitcnt vmcnt(0)" ::: "memory"); }
    __builtin_amdgcn_sched_barrier(0);
    storeB(kt + 1, rbO0, rbO1);
    asm volatile("s_waitcnt lgkmcnt(0)" ::: "memory");
    __builtin_amdgcn_sched_barrier(0);
    __builtin_amdgcn_s_barrier();
    __builtin_amdgcn_sched_barrier(0);
    if (kt + 3 < KT) { stageA(kt + 3, bufW); loadB(kt + 3, rbO0, rbO1); }
    __builtin_amdgcn_sched_barrier(0);
    computeTile(bufC, 1);
    bufC = (bufC == 2) ? 0 : bufC + 1;
    bufW = (bufW == 2) ? 0 : bufW + 1;
  }

  // epilogue; C/D layout: col = lane&15, row = (lane>>4)*4 + i (verified)
#pragma unroll
  for (int m = 0; m < 2; ++m) {
#pragma unroll
    for (int i = 0; i < 4; ++i) {
      int row = rowBase + wr * 32 + m * 16 + (lane >> 4) * 4 + i;
      if (row < rows) {
        if constexpr (EPI == 1) {
          int pair = slot_tok[e * CAP + row];
          float w = slot_w[e * CAP + row];
#pragma unroll
          for (int n = 0; n < NF; ++n) {
            int col = nBase + wc * 64 + n * 16 + (lane & 15);
            OutH[(long long)pair * DD + col] = (_Float16)(w * accG[m][n][i]);
          }
        } else if constexpr (EPI == 2) {
          float g = shg[row];
#pragma unroll
          for (int n = 0; n < NF; ++n) {
            int col = nBase + wc * 64 + n * 16 + (lane & 15);
            OutF[(long long)row * DD + col] += g * accG[m][n][i];
          }
        } else {
          long long outBase = (long long)e * strideOE;
#pragma unroll
          for (int n = 0; n < NF; ++n) {
            int col = nBase + (DUAL ? wc * 32 : wc * 64) + n * 16 + (lane & 15);
            long long o = outBase + (long long)row * ldOut + col;
            if constexpr (DUAL) {
              float gv = accG[m][n][i];
              float uv = accU[m][n][i];
              OutH[o] = (_Float16)((gv / (1.f + __expf(-gv))) * uv);
            } else {
              OutH[o] = (_Float16)accG[m][n][i];
            }
          }
        }
      }
    }
  }
}

// ---------------- combine: out[t] = sum_k (pos<CAP) Yp[t*8+k] ----------------
__global__ __launch_bounds__(256) void k_combine(
    const _Float16* __restrict__ Yp, const int* __restrict__ pair_pos,
    float* __restrict__ out) {
  int t = blockIdx.x;
  int col = threadIdx.x * 8;
  float acc[8] = {0.f, 0.f, 0.f, 0.f, 0.f, 0.f, 0.f, 0.f};
#pragma unroll
  for (int k = 0; k < KTOP; ++k) {
    if (pair_pos[t * KTOP + k] < CAP) {
      half8 y = *(const half8*)&Yp[((size_t)t * KTOP + k) * DD + col];
#pragma unroll
      for (int j = 0; j < 8; ++j) acc[j] += (float)y[j];
    }
  }
  float4 o0 = {acc[0], acc[1], acc[2], acc[3]};
  float4 o1 = {acc[4], acc[5], acc[6], acc[7]};
  *(float4*)&out[(size_t)t * DD + col] = o0;
  *(float4*)&out[(size_t)t * DD + col + 4] = o1;
}

// ---------------------------------------------------------------------------
extern "C" void kernel_launch(void* const* d_in, const int* in_sizes, int n_in,
                              void* d_out, int out_size, void* d_ws, size_t ws_size,
                              hipStream_t stream) {
  (void)in_sizes; (void)n_in; (void)out_size; (void)ws_size;
  const float* x    = (const float*)d_in[0];
  const float* rw   = (const float*)d_in[1];
  const float* wg   = (const float*)d_in[2];
  const float* sg   = (const float*)d_in[3];
  const float* wu   = (const float*)d_in[4];
  const float* su   = (const float*)d_in[5];
  const float* wd   = (const float*)d_in[6];
  const float* sd   = (const float*)d_in[7];
  const float* wsg  = (const float*)d_in[8];
  const float* wsu  = (const float*)d_in[9];
  const float* wsd  = (const float*)d_in[10];
  const float* wshg = (const float*)d_in[11];
  float* out = (float*)d_out;

  // workspace (~134.5 MB)
  char* p = (char*)d_ws;
  auto alloc = [&](size_t bytes) {
    char* r = p;
    p += (bytes + 255) & ~(size_t)255;
    return r;
  };
  _Float16* x_h   = (_Float16*)alloc((size_t)TT * DD * 2);
  _Float16* H     = (_Float16*)alloc((size_t)EE * CAP * DFF * 2);
  _Float16* Hsh   = (_Float16*)alloc((size_t)TT * DSH * 2);
  _Float16* Yp    = (_Float16*)alloc((size_t)TT * KTOP * DD * 2);
  float* shg      = (float*)alloc((size_t)TT * 4);
  int* cnt        = (int*)alloc((size_t)EE * 4);
  int* slot_tok   = (int*)alloc((size_t)EE * CAP * 4);
  float* slot_w   = (float*)alloc((size_t)EE * CAP * 4);
  int* slot_pair  = (int*)alloc((size_t)EE * CAP * 4);
  int* pair_pos   = (int*)alloc((size_t)TT * KTOP * 4);

  k_init<<<(EE * CAP + 255) / 256, 256, 0, stream>>>(cnt, slot_tok);
  k_cast<<<(TT * DD / 4) / 256, 256, 0, stream>>>(x, x_h);
  k_router<<<TT, 64, 0, stream>>>(x, rw, wshg, shg, cnt, slot_tok, slot_w,
                                  slot_pair, pair_pos);

  // routed gate+up: NP=12, MB=8, E=32 -> 3072 blocks, 512 thr
  k_gemm<true, true, true, 0, 12, 8, DD><<<3072, 512, 0, stream>>>(
      x_h, wg, wu, sg, su, DD / 128, (DFF / 128) * (DD / 128),
      H, nullptr, nullptr,
      DD, DFF,
      0LL, (long long)DFF * DD, (long long)CAP * DFF,
      cnt, 0, slot_tok, nullptr);

  // routed down -> Yp (atomic-free; pair map via slot_tok arg): 4096 blocks
  k_gemm<false, false, true, 1, 16, 8, DFF><<<4096, 512, 0, stream>>>(
      H, wd, wd, sd, sd, DFF / 128, (DD / 128) * (DFF / 128),
      Yp, nullptr, nullptr,
      DFF, DD,
      (long long)CAP * DFF, (long long)DD * DFF, 0LL,
      cnt, 0, slot_pair, slot_w);

  k_combine<<<TT, 256, 0, stream>>>(Yp, pair_pos, out);

  // shared gate+up: NP=32, MB=16, E=1 -> 512 blocks
  k_gemm<true, false, false, 0, 32, 16, DD><<<512, 512, 0, stream>>>(
      x_h, wsg, wsu, nullptr, nullptr, 0, 0,
      Hsh, nullptr, nullptr,
      DD, DSH,
      0LL, 0LL, 0LL,
      nullptr, TT, nullptr, nullptr);

  // shared down (out += shg*val, runs last): NP=16, MB=16, E=1 -> 256 blocks
  k_gemm<false, false, false, 2, 16, 16, DSH><<<256, 512, 0, stream>>>(
      Hsh, wsd, wsd, nullptr, nullptr, 0, 0,
      nullptr, out, shg,
      DSH, DD,
      0LL, 0LL, 0LL,
      nullptr, TT, nullptr, nullptr);
}